// Round 4
// baseline (314.153 us; speedup 1.0000x reference)
//
#include <hip/hip_runtime.h>

#define D 512
#define NROWS 8192
#define MROWS 8192
#define NCHUNK 8
#define CHUNK_COLS (MROWS / NCHUNK)   // 1024
#define SUBTILES (CHUNK_COLS / 128)   // 8
#define KT64 (D / 64)                 // 8 k-iterations of BK=64
#define LOG2E 1.4426950408889634f
#define LN2 0.6931471805599453f

typedef float floatx4 __attribute__((ext_vector_type(4)));
typedef __bf16 bf16x8 __attribute__((ext_vector_type(8)));
typedef unsigned short ushortx4 __attribute__((ext_vector_type(4)));

typedef __attribute__((address_space(1))) void* as1_void_p;
typedef __attribute__((address_space(3))) void* as3_void_p;

__device__ __forceinline__ void async_cp16(const void* g, void* l) {
    __builtin_amdgcn_global_load_lds((as1_void_p)(void*)g, (as3_void_p)l, 16, 0, 0);
}

__device__ __forceinline__ unsigned short f2bf(float f) {
    unsigned u = __float_as_uint(f);
    u += 0x7fffu + ((u >> 16) & 1u);
    return (unsigned short)(u >> 16);
}
__device__ __forceinline__ float bf2f(unsigned short h) {
    return __uint_as_float(((unsigned)h) << 16);
}

__device__ __forceinline__ float fast_tanh(float x) {
    const float xc = fminf(fmaxf(x, -15.0f), 15.0f);
    const float e = __builtin_exp2f(xc * (2.0f * LOG2E));
    return (e - 1.0f) * __builtin_amdgcn_rcpf(e + 1.0f);
}

// ---------------------------------------------------------------------------
// Kernel 1 (fused prep): x -> bf16(x*log2e) + ||x||^2; mu -> bf16; W -> bf16;
// zero fsq, chunk-counters, out.
#define NB_X NROWS
#define NB_MU (MROWS * D / 1024)      // 4096
#define NB_W (D * D / 1024)           // 256
__global__ void k_prep(const float* __restrict__ x,
                       const float* __restrict__ mu,
                       const float* __restrict__ W,
                       unsigned short* __restrict__ xb,
                       unsigned short* __restrict__ mub,
                       unsigned short* __restrict__ Wb,
                       float* __restrict__ xsq,
                       float* __restrict__ fsq,
                       int* __restrict__ cnt,
                       float* __restrict__ out) {
    const int bid = blockIdx.x;
    const int t = threadIdx.x;  // 256
    if (bid < NB_X) {
        if (bid == 0 && t == 0) out[0] = 0.f;
        const float2 v = ((const float2*)(x + (size_t)bid * D))[t];
        const unsigned short b0 = f2bf(v.x * LOG2E), b1 = f2bf(v.y * LOG2E);
        ((unsigned*)(xb + (size_t)bid * D))[t] = (unsigned)b0 | ((unsigned)b1 << 16);
        float s = v.x * v.x + v.y * v.y;
        #pragma unroll
        for (int m = 1; m < 64; m <<= 1) s += __shfl_xor(s, m);
        __shared__ float ws4[4];
        if ((t & 63) == 0) ws4[t >> 6] = s;
        __syncthreads();
        if (t == 0) xsq[bid] = ws4[0] + ws4[1] + ws4[2] + ws4[3];
    } else if (bid < NB_X + NB_MU) {
        const int i = (bid - NB_X) * 256 + t;
        const float4 v = ((const float4*)mu)[i];
        ushortx4 o;
        o.x = f2bf(v.x); o.y = f2bf(v.y); o.z = f2bf(v.z); o.w = f2bf(v.w);
        ((ushortx4*)mub)[i] = o;
    } else {
        const int wb_blk = bid - NB_X - NB_MU;
        const int i = wb_blk * 256 + t;
        const float4 v = ((const float4*)W)[i];
        ushortx4 o;
        o.x = f2bf(v.x); o.y = f2bf(v.y); o.z = f2bf(v.z); o.w = f2bf(v.w);
        ((ushortx4*)Wb)[i] = o;
        if (t < 32) fsq[wb_blk * 32 + t] = 0.f;
        if (wb_blk == 0 && t >= 64 && t < 64 + NROWS / 128) cnt[t - 64] = 0;
    }
}

// ---------------------------------------------------------------------------
// Kernel 2: f = tanh(mu @ W^T + b) -> bf16; fused row ||f||^2 via atomics.
// BK=64 (two 32-k halves per barrier), XOR-swizzled LDS.
__global__ __launch_bounds__(256, 2)
void k_fgemm(const unsigned short* __restrict__ mub,
             const unsigned short* __restrict__ Wb,
             const float* __restrict__ bias,
             unsigned short* __restrict__ fb,
             float* __restrict__ fsq) {
    __shared__ unsigned short Ab[2][128 * 32];
    __shared__ unsigned short Bb[2][128 * 32];

    const int tid = threadIdx.x;
    const int wave = tid >> 6;
    const int lane = tid & 63;
    const int wr = wave >> 1, wc = wave & 1;
    const int g = lane >> 4;
    const int lm = lane & 15;

    const int row0 = blockIdx.x * 128;
    const int col0 = blockIdx.y * 128;

    const int srow = tid >> 2;
    const int gsrc = (tid & 3) ^ ((srow >> 1) & 3);
    const unsigned short* gA = mub + (size_t)(row0 + srow) * D + gsrc * 8;
    const unsigned short* gB = Wb  + (size_t)(col0 + srow) * D + gsrc * 8;
    char* lA = ((char*)Ab[0]) + wave * 1024;
    char* lB = ((char*)Bb[0]) + wave * 1024;

    const int xsel = (lm >> 1) & 3;
    const unsigned short* fragA = Ab[0] + (64 * wr + lm) * 32 + (g ^ xsel) * 8;
    const unsigned short* fragB = Bb[0] + (64 * wc + lm) * 32 + (g ^ xsel) * 8;

    floatx4 acc[4][4];
    const floatx4 zz = {0.f, 0.f, 0.f, 0.f};
    #pragma unroll
    for (int i = 0; i < 4; ++i)
        #pragma unroll
        for (int j = 0; j < 4; ++j) acc[i][j] = zz;

    for (int kt = 0; kt < KT64; ++kt) {
        const int k0 = kt * 64;
        #pragma unroll
        for (int h = 0; h < 2; ++h) {
            async_cp16(gA + k0 + 32 * h, lA + 8192 * h);
            async_cp16(gA + 64 * D + k0 + 32 * h, lA + 8192 * h + 4096);
            async_cp16(gB + k0 + 32 * h, lB + 8192 * h);
            async_cp16(gB + 64 * D + k0 + 32 * h, lB + 8192 * h + 4096);
        }
        __syncthreads();
        #pragma unroll
        for (int h = 0; h < 2; ++h) {
            const unsigned short* fA = fragA + h * 4096;
            const unsigned short* fB = fragB + h * 4096;
            bf16x8 af0 = *(const bf16x8*)(fA);
            bf16x8 af1 = *(const bf16x8*)(fA + 512);
            bf16x8 af2 = *(const bf16x8*)(fA + 1024);
            bf16x8 af3 = *(const bf16x8*)(fA + 1536);
            #pragma unroll
            for (int j = 0; j < 4; ++j) {
                const bf16x8 bj = *(const bf16x8*)(fB + j * 512);
                acc[0][j] = __builtin_amdgcn_mfma_f32_16x16x32_bf16(af0, bj, acc[0][j], 0, 0, 0);
                acc[1][j] = __builtin_amdgcn_mfma_f32_16x16x32_bf16(af1, bj, acc[1][j], 0, 0, 0);
                acc[2][j] = __builtin_amdgcn_mfma_f32_16x16x32_bf16(af2, bj, acc[2][j], 0, 0, 0);
                acc[3][j] = __builtin_amdgcn_mfma_f32_16x16x32_bf16(af3, bj, acc[3][j], 0, 0, 0);
            }
        }
        __syncthreads();
    }

    float bcol[4];
    #pragma unroll
    for (int j = 0; j < 4; ++j) bcol[j] = bias[col0 + 64 * wc + 16 * j + lm];
    #pragma unroll
    for (int i = 0; i < 4; ++i) {
        #pragma unroll
        for (int r = 0; r < 4; ++r) {
            const int row = row0 + 64 * wr + 16 * i + 4 * g + r;
            float sq = 0.f;
            #pragma unroll
            for (int j = 0; j < 4; ++j) {
                const int col = col0 + 64 * wc + 16 * j + lm;
                const unsigned short h = f2bf(fast_tanh(acc[i][j][r] + bcol[j]));
                fb[(size_t)row * D + col] = h;
                const float fr = bf2f(h);
                sq += fr * fr;
            }
            #pragma unroll
            for (int d = 1; d < 16; d <<= 1) sq += __shfl_xor(sq, d);
            if (lm == 0) atomicAdd(fsq + row, sq);
        }
    }
}

// ---------------------------------------------------------------------------
// Kernel 3: fused cross-GEMM + per-lane online logsumexp + fused finish.
// BK=64; last chunk-block per row-block combines partials and adds to out.
__global__ __launch_bounds__(256, 3)
void k_cross(const unsigned short* __restrict__ xb,
             const unsigned short* __restrict__ fb,
             const float* __restrict__ fsq,
             const float* __restrict__ xsq,
             float* __restrict__ pmax,
             float* __restrict__ psum,
             int* __restrict__ cnt,
             float* __restrict__ out) {
    __shared__ unsigned short Ab[2][128 * 32];
    __shared__ unsigned short Bb[2][128 * 32];
    __shared__ float mbuf[128], sbuf[128];
    __shared__ int is_last;

    const int tid = threadIdx.x;
    const int wave = tid >> 6;
    const int lane = tid & 63;
    const int wr = wave >> 1, wc = wave & 1;
    const int g = lane >> 4;
    const int lm = lane & 15;

    const int row0 = blockIdx.x * 128;
    const int chunk = blockIdx.y;

    const int srow = tid >> 2;
    const int gsrc = (tid & 3) ^ ((srow >> 1) & 3);
    const unsigned short* gA = xb + (size_t)(row0 + srow) * D + gsrc * 8;
    char* lA = ((char*)Ab[0]) + wave * 1024;
    char* lB = ((char*)Bb[0]) + wave * 1024;

    const int xsel = (lm >> 1) & 3;
    const unsigned short* fragA = Ab[0] + (64 * wr + lm) * 32 + (g ^ xsel) * 8;
    const unsigned short* fragB = Bb[0] + (64 * wc + lm) * 32 + (g ^ xsel) * 8;

    float m_loc[4][4], s_loc[4][4];
    #pragma unroll
    for (int i = 0; i < 4; ++i)
        #pragma unroll
        for (int r = 0; r < 4; ++r) { m_loc[i][r] = -__builtin_inff(); s_loc[i][r] = 0.f; }

    for (int st = 0; st < SUBTILES; ++st) {
        const int col0 = chunk * CHUNK_COLS + st * 128;
        const unsigned short* gB = fb + (size_t)(col0 + srow) * D + gsrc * 8;

        floatx4 acc[4][4];
        const floatx4 zz = {0.f, 0.f, 0.f, 0.f};
        #pragma unroll
        for (int i = 0; i < 4; ++i)
            #pragma unroll
            for (int j = 0; j < 4; ++j) acc[i][j] = zz;

        for (int kt = 0; kt < KT64; ++kt) {
            const int k0 = kt * 64;
            #pragma unroll
            for (int h = 0; h < 2; ++h) {
                async_cp16(gA + k0 + 32 * h, lA + 8192 * h);
                async_cp16(gA + 64 * D + k0 + 32 * h, lA + 8192 * h + 4096);
                async_cp16(gB + k0 + 32 * h, lB + 8192 * h);
                async_cp16(gB + 64 * D + k0 + 32 * h, lB + 8192 * h + 4096);
            }
            __syncthreads();
            #pragma unroll
            for (int h = 0; h < 2; ++h) {
                const unsigned short* fA = fragA + h * 4096;
                const unsigned short* fB = fragB + h * 4096;
                bf16x8 af0 = *(const bf16x8*)(fA);
                bf16x8 af1 = *(const bf16x8*)(fA + 512);
                bf16x8 af2 = *(const bf16x8*)(fA + 1024);
                bf16x8 af3 = *(const bf16x8*)(fA + 1536);
                #pragma unroll
                for (int j = 0; j < 4; ++j) {
                    const bf16x8 bj = *(const bf16x8*)(fB + j * 512);
                    acc[0][j] = __builtin_amdgcn_mfma_f32_16x16x32_bf16(af0, bj, acc[0][j], 0, 0, 0);
                    acc[1][j] = __builtin_amdgcn_mfma_f32_16x16x32_bf16(af1, bj, acc[1][j], 0, 0, 0);
                    acc[2][j] = __builtin_amdgcn_mfma_f32_16x16x32_bf16(af2, bj, acc[2][j], 0, 0, 0);
                    acc[3][j] = __builtin_amdgcn_mfma_f32_16x16x32_bf16(af3, bj, acc[3][j], 0, 0, 0);
                }
            }
            __syncthreads();
        }

        float hf[4];
        #pragma unroll
        for (int j = 0; j < 4; ++j)
            hf[j] = 0.5f * LOG2E * fsq[col0 + 64 * wc + 16 * j + lm];
        #pragma unroll
        for (int i = 0; i < 4; ++i) {
            #pragma unroll
            for (int r = 0; r < 4; ++r) {
                const float v0 = acc[i][0][r] - hf[0];
                const float v1 = acc[i][1][r] - hf[1];
                const float v2 = acc[i][2][r] - hf[2];
                const float v3 = acc[i][3][r] - hf[3];
                const float mm = fmaxf(fmaxf(v0, v1), fmaxf(v2, v3));
                const float nm = fmaxf(m_loc[i][r], mm);
                s_loc[i][r] = s_loc[i][r] * __builtin_exp2f(m_loc[i][r] - nm)
                            + __builtin_exp2f(v0 - nm) + __builtin_exp2f(v1 - nm)
                            + __builtin_exp2f(v2 - nm) + __builtin_exp2f(v3 - nm);
                m_loc[i][r] = nm;
            }
        }
    }

    // merge across 16-lane group
    #pragma unroll
    for (int i = 0; i < 4; ++i) {
        #pragma unroll
        for (int r = 0; r < 4; ++r) {
            float m = m_loc[i][r], s = s_loc[i][r];
            #pragma unroll
            for (int d = 1; d < 16; d <<= 1) {
                const float om = __shfl_xor(m, d);
                const float os = __shfl_xor(s, d);
                const float nm = fmaxf(m, om);
                s = s * __builtin_exp2f(m - nm) + os * __builtin_exp2f(om - nm);
                m = nm;
            }
            m_loc[i][r] = m; s_loc[i][r] = s;
        }
    }
    // merge the two column-waves via LDS, write partials
    if (wc == 0 && lm == 0) {
        #pragma unroll
        for (int i = 0; i < 4; ++i)
            #pragma unroll
            for (int r = 0; r < 4; ++r) {
                const int rl = 64 * wr + 16 * i + 4 * g + r;
                mbuf[rl] = m_loc[i][r]; sbuf[rl] = s_loc[i][r];
            }
    }
    __syncthreads();
    if (wc == 1 && lm == 0) {
        #pragma unroll
        for (int i = 0; i < 4; ++i)
            #pragma unroll
            for (int r = 0; r < 4; ++r) {
                const int rl = 64 * wr + 16 * i + 4 * g + r;
                const float om = mbuf[rl], os = sbuf[rl];
                float m = m_loc[i][r], s = s_loc[i][r];
                const float nm = fmaxf(m, om);
                s = s * __builtin_exp2f(m - nm) + os * __builtin_exp2f(om - nm);
                pmax[(size_t)(row0 + rl) * NCHUNK + chunk] = nm;
                psum[(size_t)(row0 + rl) * NCHUNK + chunk] = s;
            }
    }

    // ---- fused finish: last chunk-block for this row-block combines.
    __threadfence();
    __syncthreads();
    if (tid == 0) {
        const int old = __hip_atomic_fetch_add(&cnt[blockIdx.x], 1,
                                               __ATOMIC_ACQ_REL, __HIP_MEMORY_SCOPE_AGENT);
        is_last = (old == NCHUNK - 1) ? 1 : 0;
    }
    __syncthreads();
    if (!is_last) return;
    __threadfence();

    float lse = 0.f;
    if (tid < 128) {
        const int row = row0 + tid;
        const float* pm = pmax + (size_t)row * NCHUNK;
        const float* ps = psum + (size_t)row * NCHUNK;
        float gm = -__builtin_inff();
        #pragma unroll
        for (int c = 0; c < NCHUNK; ++c) gm = fmaxf(gm, pm[c]);
        float s = 0.f;
        #pragma unroll
        for (int c = 0; c < NCHUNK; ++c) s += ps[c] * __builtin_exp2f(pm[c] - gm);
        lse = LN2 * (gm + __builtin_log2f(s)) - 0.5f * xsq[row];
    }
    #pragma unroll
    for (int m = 1; m < 64; m <<= 1) lse += __shfl_xor(lse, m);
    if (lane == 0) mbuf[wave] = lse;
    __syncthreads();
    if (tid == 0) atomicAdd(out, -(mbuf[0] + mbuf[1]));
}

// ---------------------------------------------------------------------------
extern "C" void kernel_launch(void* const* d_in, const int* in_sizes, int n_in,
                              void* d_out, int out_size, void* d_ws, size_t ws_size,
                              hipStream_t stream) {
    const float* x  = (const float*)d_in[0];   // (8192, 512)
    const float* mu = (const float*)d_in[1];   // (8192, 512)
    const float* W  = (const float*)d_in[2];   // (512, 512)
    const float* b  = (const float*)d_in[3];   // (512,)

    char* ws = (char*)d_ws;
    unsigned short* xb  = (unsigned short*)(ws);                    // 8 MB
    unsigned short* fb  = (unsigned short*)(ws + (8u << 20));       // 8 MB
    unsigned short* mub = (unsigned short*)(ws + (16u << 20));      // 8 MB
    unsigned short* Wb  = (unsigned short*)(ws + (24u << 20));      // 512 KB
    float* xsq  = (float*)(ws + (25u << 20));                       // 32 KB
    float* fsq  = xsq + NROWS;                                      // 32 KB
    float* pmax = fsq + MROWS;                                      // 256 KB
    float* psum = pmax + (size_t)NROWS * NCHUNK;                    // 256 KB
    int*   cnt  = (int*)(psum + (size_t)NROWS * NCHUNK);            // 256 B

    float* out = (float*)d_out;

    hipLaunchKernelGGL(k_prep, dim3(NB_X + NB_MU + NB_W), dim3(256), 0, stream,
                       x, mu, W, xb, mub, Wb, xsq, fsq, cnt, out);
    hipLaunchKernelGGL(k_fgemm, dim3(MROWS / 128, D / 128), dim3(256), 0, stream,
                       mub, Wb, b, fb, fsq);
    hipLaunchKernelGGL(k_cross, dim3(NROWS / 128, NCHUNK), dim3(256), 0, stream,
                       xb, fb, fsq, xsq, pmax, psum, cnt, out);
}